// Round 5
// baseline (453.962 us; speedup 1.0000x reference)
//
#include <hip/hip_runtime.h>
#include <hip/hip_bf16.h>
#include <stdint.h>

// ImprovedLatticeRNNCell fused bf16-MFMA implementation, round 5.
// B=16384, IN=128, H=512, NH=4, HD=128.
// GEMM: 256x256 tile, BK=64, 512 threads (8 waves 2x4), double-buffered LDS
// (128 KiB), counted vmcnt(8) [8 loads/stage], both-sides XOR swizzle,
// XCD block swizzle.

#define NB 16384
#define NHEADS 4

typedef __attribute__((ext_vector_type(8))) __bf16 bf16x8;
typedef __attribute__((ext_vector_type(4))) float f32x4;
typedef __attribute__((ext_vector_type(8))) unsigned short u16x8;

__device__ __forceinline__ unsigned short f2bf(float f) {
  union { float f; unsigned int u; } v; v.f = f;
  unsigned int u = v.u;
  unsigned int r = (u + 0x7fffu + ((u >> 16) & 1u)) >> 16;
  return (unsigned short)r;
}
__device__ __forceinline__ float bf2f(unsigned short h) {
  union { unsigned int u; float f; } v; v.u = ((unsigned int)h) << 16;
  return v.f;
}
__device__ __forceinline__ float sigmoidf_(float x) {
  return 1.0f / (1.0f + __expf(-x));
}

// ---------------- merged f32 -> bf16 conversion (9 jobs, 1 launch) ----------
// sizes compile-time (units of 8 elems):
#define J0 (512 * 128 / 8)    // W_in -> wComb head
#define J1 (1536 * 128 / 8)   // gru_w_ih -> wComb tail
#define J2 (1536 * 512 / 8)   // attn_in_w
#define J3 (512 * 512 / 8)    // attn_out_w
#define J4 (512 * 1536 / 8)   // W_gate
#define J5 (1536 * 512 / 8)   // gru_w_hh
#define J6 (NB * 128 / 8)     // x
#define J7 (NB * 512 / 8)     // hl
#define J8 (NB * 512 / 8)     // hu
#define C1 (J0)
#define C2 (C1 + J1)
#define C3 (C2 + J2)
#define C4 (C3 + J3)
#define C5 (C4 + J4)
#define C6 (C5 + J5)
#define C7 (C6 + J6)
#define C8 (C7 + J7)
#define CT (C8 + J8)

struct CvtJobs {
  const float* src[9];
  unsigned short* dst[9];
};

__global__ void cvt_multi(CvtJobs j) {
  int g = blockIdx.x * blockDim.x + threadIdx.x;
  if (g >= CT) return;
  int k, base;
  if (g < C4) {
    if (g < C2) {
      if (g < C1) { k = 0; base = 0; } else { k = 1; base = C1; }
    } else {
      if (g < C3) { k = 2; base = C2; } else { k = 3; base = C3; }
    }
  } else {
    if (g < C6) {
      if (g < C5) { k = 4; base = C4; } else { k = 5; base = C5; }
    } else {
      if (g < C7) { k = 6; base = C6; }
      else if (g < C8) { k = 7; base = C7; }
      else { k = 8; base = C8; }
    }
  }
  int local = g - base;
  const float4* s = (const float4*)j.src[k] + (size_t)local * 2;
  float4 a = s[0], b = s[1];
  u16x8 o;
  o[0] = f2bf(a.x); o[1] = f2bf(a.y); o[2] = f2bf(a.z); o[3] = f2bf(a.w);
  o[4] = f2bf(b.x); o[5] = f2bf(b.y); o[6] = f2bf(b.z); o[7] = f2bf(b.w);
  *((u16x8*)j.dst[k] + local) = o;
}

// pack hidden_prev f32 [B,512] -> bf16 into gate_in [B,1536] cols 0..511
__global__ void pack_hp(const float* __restrict__ hp,
                        unsigned short* __restrict__ gate_in) {
  int t = blockIdx.x * blockDim.x + threadIdx.x;  // B*64 threads
  int b = t >> 6;
  int j = (t & 63) * 8;
  const float4* s = (const float4*)(hp + (size_t)b * 512 + j);
  float4 a = s[0], c = s[1];
  u16x8 o;
  o[0] = f2bf(a.x); o[1] = f2bf(a.y); o[2] = f2bf(a.z); o[3] = f2bf(a.w);
  o[4] = f2bf(c.x); o[5] = f2bf(c.y); o[6] = f2bf(c.z); o[7] = f2bf(c.w);
  *(u16x8*)(gate_in + (size_t)b * 1536 + j) = o;
}

// ---------------- GEMM: C[M,N] = A[M,K](bf16) * W[N,K]^T(bf16) + bias ----------------
__device__ __forceinline__ void gl_lds16(const unsigned short* g, unsigned short* l) {
  __builtin_amdgcn_global_load_lds(
      (const __attribute__((address_space(1))) void*)g,
      (__attribute__((address_space(3))) void*)l, 16, 0, 0);
}

// EPI 0: outb[row*ldob+col] = bf16(v)
// EPI 1: gate epilogue (sigmoid, enhanced blend) -> outf(f32) + outb(bf16)
// EPI 2: router: col<512 -> outb (ldob, bias), else outb2 at col-512 (ldob2, bias2)
template <int EPI>
__global__ __launch_bounds__(512, 2) void gemm_bt(
    const unsigned short* __restrict__ A, int lda,
    const unsigned short* __restrict__ W, int ldw,
    const float* __restrict__ bias, const float* __restrict__ bias2,
    int K, int ntx,
    unsigned short* __restrict__ outb, int ldob,
    unsigned short* __restrict__ outb2, int ldob2,
    float* __restrict__ outf,
    const float* __restrict__ hp,
    const unsigned short* __restrict__ scb) {
  __shared__ unsigned short As[2][256 * 64];
  __shared__ unsigned short Ws[2][256 * 64];
  const int tid = threadIdx.x;
  const int lane = tid & 63;
  const int wave = tid >> 6;  // 0..7

  // XCD-aware bijective swizzle (gridDim.x always a multiple of 8 here)
  const int nwg = gridDim.x;
  const int cpx = nwg >> 3;
  const int bid = blockIdx.x;
  const int id = (bid & 7) * cpx + (bid >> 3);
  const int bx = id % ntx;
  const int by = id / ntx;

  const int m0 = by * 256;
  const int n0 = bx * 256;
  const int wm = (wave >> 2) * 128;  // 2 M-halves
  const int wn = (wave & 3) * 64;    // 4 N-quarters

  f32x4 acc[8][4] = {};

  // staging: thread covers (row = srow + 64*i, 16B slot sslot); source slot
  // pre-swizzled so that swizzled ds_read sees conflict-free layout.
  const int srow = tid >> 3;                 // 0..63
  const int sslot = (tid & 7) ^ (srow & 7);  // inverse-swizzled source slot
  const unsigned short* Ag = A + (size_t)(m0 + srow) * lda + sslot * 8;
  const unsigned short* Wg = W + (size_t)(n0 + srow) * ldw + sslot * 8;
  unsigned short* Asd = &As[0][tid * 8];
  unsigned short* Wsd = &Ws[0][tid * 8];

  auto stage = [&](int buf, int k0) {
#pragma unroll
    for (int i = 0; i < 4; ++i)
      gl_lds16(Ag + (size_t)(i * 64) * lda + k0, Asd + buf * 16384 + i * 4096);
#pragma unroll
    for (int i = 0; i < 4; ++i)
      gl_lds16(Wg + (size_t)(i * 64) * ldw + k0, Wsd + buf * 16384 + i * 4096);
  };

  stage(0, 0);
  int cur = 0;
  const int lrow = lane & 15;
  const int kq = (lane >> 4) * 8;  // shorts
  const int sw = (lrow & 7) << 3;  // read-side swizzle (shorts)

  for (int k0 = 0; k0 < K; k0 += 64) {
    if (k0 + 64 < K) {
      stage(cur ^ 1, k0 + 64);
      // 8 loads/stage: wait for the 8 oldest (current buffer), keep 8 in flight
      asm volatile("s_waitcnt vmcnt(8)" ::: "memory");
    } else {
      asm volatile("s_waitcnt vmcnt(0)" ::: "memory");
    }
    __builtin_amdgcn_s_barrier();
#pragma unroll
    for (int kk = 0; kk < 2; ++kk) {
      const int kr = kk * 32 + kq;
      const int ki = kr ^ sw;
      bf16x8 af[8], wf[4];
#pragma unroll
      for (int m = 0; m < 8; ++m)
        af[m] = *(const bf16x8*)&As[cur][(wm + m * 16 + lrow) * 64 + ki];
#pragma unroll
      for (int n = 0; n < 4; ++n)
        wf[n] = *(const bf16x8*)&Ws[cur][(wn + n * 16 + lrow) * 64 + ki];
#pragma unroll
      for (int m = 0; m < 8; ++m)
#pragma unroll
        for (int n = 0; n < 4; ++n)
          acc[m][n] = __builtin_amdgcn_mfma_f32_16x16x32_bf16(af[m], wf[n],
                                                              acc[m][n], 0, 0, 0);
    }
    __builtin_amdgcn_s_barrier();
    cur ^= 1;
  }

  const int r0 = m0 + wm + ((lane >> 4) << 2);
  const int c0 = n0 + wn + lrow;

  // EPI==2 routing is uniform per block (n0 multiple of 256, split at 512)
  unsigned short* ob = outb;
  int ld = ldob, cof = 0;
  const float* bp = bias;
  if constexpr (EPI == 2) {
    if (n0 >= 512) { ob = outb2; ld = ldob2; cof = -512; bp = bias2; }
  }

#pragma unroll
  for (int n = 0; n < 4; ++n) {
    const int col = c0 + n * 16;
    float bv;
    if constexpr (EPI == 2) bv = bp ? bp[col + cof] : 0.0f;
    else bv = bias ? bias[col] : 0.0f;
#pragma unroll
    for (int m = 0; m < 8; ++m) {
#pragma unroll
      for (int i = 0; i < 4; ++i) {
        const int row = r0 + m * 16 + i;
        float v = acc[m][n][i] + bv;
        if constexpr (EPI == 1) {
          // gate epilogue: g = sigmoid(v); enhanced = hp + g*sc
          float g = sigmoidf_(v);
          float sc = bf2f(scb[(size_t)row * 1536 + col]);
          float e = hp[(size_t)row * 512 + col] + g * sc;
          outf[(size_t)row * 512 + col] = e;
          outb[(size_t)row * 512 + col] = f2bf(e);
        } else {
          ob[(size_t)row * ld + col + cof] = f2bf(v);
        }
      }
    }
  }
}

// ---------------- attention over the 2 neighbor states ----------------
__global__ void attn_fuse(const unsigned short* __restrict__ qkvl,
                          const unsigned short* __restrict__ qkvu,
                          unsigned short* __restrict__ ctx) {
  int t = blockIdx.x * blockDim.x + threadIdx.x;
  int g = t >> 4;  // (b,h)
  int l = t & 15;
  int b = g >> 2, h = g & 3;
  const size_t base = (size_t)b * 1536 + h * 128 + l * 8;
  u16x8 q0 = *(const u16x8*)(qkvl + base);
  u16x8 k0 = *(const u16x8*)(qkvl + base + 512);
  u16x8 v0 = *(const u16x8*)(qkvl + base + 1024);
  u16x8 q1 = *(const u16x8*)(qkvu + base);
  u16x8 k1 = *(const u16x8*)(qkvu + base + 512);
  u16x8 v1 = *(const u16x8*)(qkvu + base + 1024);
  float s00 = 0.f, s01 = 0.f, s10 = 0.f, s11 = 0.f;
  float v0f[8], v1f[8];
#pragma unroll
  for (int i = 0; i < 8; ++i) {
    float q0f = bf2f(q0[i]), q1f = bf2f(q1[i]);
    float k0f = bf2f(k0[i]), k1f = bf2f(k1[i]);
    v0f[i] = bf2f(v0[i]); v1f[i] = bf2f(v1[i]);
    s00 += q0f * k0f; s01 += q0f * k1f;
    s10 += q1f * k0f; s11 += q1f * k1f;
  }
#pragma unroll
  for (int off = 1; off < 16; off <<= 1) {
    s00 += __shfl_xor(s00, off);
    s01 += __shfl_xor(s01, off);
    s10 += __shfl_xor(s10, off);
    s11 += __shfl_xor(s11, off);
  }
  const float scale = 0.0883883476483184f;  // 1/sqrt(128)
  s00 *= scale; s01 *= scale; s10 *= scale; s11 *= scale;
  float m0 = fmaxf(s00, s01), m1 = fmaxf(s10, s11);
  float a00 = __expf(s00 - m0), a01 = __expf(s01 - m0);
  float a10 = __expf(s10 - m1), a11 = __expf(s11 - m1);
  float c0 = 0.5f * (a00 / (a00 + a01) + a10 / (a10 + a11));
  float c1 = 0.5f * (a01 / (a00 + a01) + a11 / (a10 + a11));
  u16x8 o;
#pragma unroll
  for (int i = 0; i < 8; ++i) o[i] = f2bf(c0 * v0f[i] + c1 * v1f[i]);
  *(u16x8*)(ctx + (size_t)b * 512 + h * 128 + l * 8) = o;
}

// ---------------- GRU elementwise finish ----------------
__global__ void gru_final(const unsigned short* __restrict__ gi,
                          const unsigned short* __restrict__ gh,
                          const float* __restrict__ enh,
                          float* __restrict__ out) {
  int t = blockIdx.x * blockDim.x + threadIdx.x;  // B*64 threads
  int b = t >> 6;
  int j = (t & 63) * 8;
  size_t gb = (size_t)b * 1536 + j;
  u16x8 ir = *(const u16x8*)(gi + gb);
  u16x8 iz = *(const u16x8*)(gi + gb + 512);
  u16x8 in_ = *(const u16x8*)(gi + gb + 1024);
  u16x8 hr = *(const u16x8*)(gh + gb);
  u16x8 hz = *(const u16x8*)(gh + gb + 512);
  u16x8 hn = *(const u16x8*)(gh + gb + 1024);
  size_t eb = (size_t)b * 512 + j;
  float4 e0 = *(const float4*)(enh + eb);
  float4 e1 = *(const float4*)(enh + eb + 4);
  float ef[8] = {e0.x, e0.y, e0.z, e0.w, e1.x, e1.y, e1.z, e1.w};
  float of[8];
#pragma unroll
  for (int i = 0; i < 8; ++i) {
    float r = sigmoidf_(bf2f(ir[i]) + bf2f(hr[i]));
    float z = sigmoidf_(bf2f(iz[i]) + bf2f(hz[i]));
    float n = tanhf(bf2f(in_[i]) + r * bf2f(hn[i]));
    of[i] = (1.0f - z) * n + z * ef[i];
  }
  *(float4*)(out + eb) = make_float4(of[0], of[1], of[2], of[3]);
  *(float4*)(out + eb + 4) = make_float4(of[4], of[5], of[6], of[7]);
}

extern "C" void kernel_launch(void* const* d_in, const int* in_sizes, int n_in,
                              void* d_out, int out_size, void* d_ws, size_t ws_size,
                              hipStream_t stream) {
  const float* x = (const float*)d_in[0];
  const float* hl = (const float*)d_in[1];
  const float* hu = (const float*)d_in[2];
  const float* hp = (const float*)d_in[3];
  const float* W_in = (const float*)d_in[4];
  const float* b_in = (const float*)d_in[5];
  const float* attn_in_w = (const float*)d_in[6];
  const float* attn_in_b = (const float*)d_in[7];
  const float* attn_out_w = (const float*)d_in[8];
  const float* attn_out_b = (const float*)d_in[9];
  const float* W_gate = (const float*)d_in[10];
  const float* b_gate = (const float*)d_in[11];
  const float* gru_w_ih = (const float*)d_in[12];
  const float* gru_w_hh = (const float*)d_in[13];
  const float* gru_b_ih = (const float*)d_in[14];
  const float* gru_b_hh = (const float*)d_in[15];

  char* ws = (char*)d_ws;
  size_t off = 0;
  auto alloc = [&](size_t bytes) {
    void* p = ws + off;
    off += (bytes + 255) & ~(size_t)255;
    return p;
  };
  // bf16 weights
  unsigned short* wComb = (unsigned short*)alloc((size_t)2048 * 128 * 2);  // [W_in; gru_w_ih]
  unsigned short* wAin  = (unsigned short*)alloc((size_t)1536 * 512 * 2);
  unsigned short* wAout = (unsigned short*)alloc((size_t)512 * 512 * 2);
  unsigned short* wGate = (unsigned short*)alloc((size_t)512 * 1536 * 2);
  unsigned short* wHh   = (unsigned short*)alloc((size_t)1536 * 512 * 2);
  // bf16 activations
  unsigned short* xb   = (unsigned short*)alloc((size_t)NB * 128 * 2);
  unsigned short* hlub = (unsigned short*)alloc((size_t)2 * NB * 512 * 2);   // [hl; hu]
  unsigned short* gate_in = (unsigned short*)alloc((size_t)NB * 1536 * 2);   // [hp|sc|xp]
  unsigned short* qkvb = (unsigned short*)alloc((size_t)2 * NB * 1536 * 2);  // [qkvl; qkvu]
  unsigned short* ctxb = (unsigned short*)alloc((size_t)NB * 512 * 2);
  float* enhf = (float*)alloc((size_t)NB * 512 * 4);
  unsigned short* enhb = (unsigned short*)alloc((size_t)NB * 512 * 2);
  unsigned short* qkvl = qkvb;
  unsigned short* qkvu = qkvb + (size_t)NB * 1536;
  unsigned short* gi = qkvl;  // reuse (qkv dead after attn_fuse)
  unsigned short* gh = qkvu;

  (void)ws_size; (void)in_sizes; (void)n_in; (void)out_size;

  const int T = 256;

  // single merged conversion launch (9 jobs)
  CvtJobs jobs;
  jobs.src[0] = W_in;       jobs.dst[0] = wComb;
  jobs.src[1] = gru_w_ih;   jobs.dst[1] = wComb + (size_t)512 * 128;
  jobs.src[2] = attn_in_w;  jobs.dst[2] = wAin;
  jobs.src[3] = attn_out_w; jobs.dst[3] = wAout;
  jobs.src[4] = W_gate;     jobs.dst[4] = wGate;
  jobs.src[5] = gru_w_hh;   jobs.dst[5] = wHh;
  jobs.src[6] = x;          jobs.dst[6] = xb;
  jobs.src[7] = hl;         jobs.dst[7] = hlub;
  jobs.src[8] = hu;         jobs.dst[8] = hlub + (size_t)NB * 512;
  cvt_multi<<<(CT + T - 1) / T, T, 0, stream>>>(jobs);
  pack_hp<<<NB * 64 / T, T, 0, stream>>>(hp, gate_in);

  const int MT = NB / 256;  // 64 M-tiles

  // G2 batched: qkv for [hl;hu], M=2*NB -> 128 M-tiles x 6 N-tiles
  gemm_bt<0><<<6 * 2 * MT, dim3(512), 0, stream>>>(hlub, 512, wAin, 512, attn_in_b,
                                                   nullptr, 512, 6,
                                                   qkvb, 1536, nullptr, 0,
                                                   nullptr, nullptr, nullptr);
  // attention -> ctx_mean (bf16)
  attn_fuse<<<NB * NHEADS * 16 / T, T, 0, stream>>>(qkvl, qkvu, ctxb);
  // G4: spatial_combined -> gate_in cols 512..1023
  gemm_bt<0><<<2 * MT, dim3(512), 0, stream>>>(ctxb, 512, wAout, 512, attn_out_b,
                                               nullptr, 512, 2,
                                               gate_in + 512, 1536, nullptr, 0,
                                               nullptr, nullptr, nullptr);
  // G1+G6 fused: x @ [W_in; w_ih]^T, N=2048; cols<512 -> gate_in+1024, else gi
  gemm_bt<2><<<8 * MT, dim3(512), 0, stream>>>(xb, 128, wComb, 128, b_in,
                                               gru_b_ih, 128, 8,
                                               gate_in + 1024, 1536, gi, 1536,
                                               nullptr, nullptr, nullptr);
  // G5: gate + enhanced
  gemm_bt<1><<<2 * MT, dim3(512), 0, stream>>>(gate_in, 1536, wGate, 1536, b_gate,
                                               nullptr, 1536, 2,
                                               enhb, 512, nullptr, 0,
                                               enhf, hp, gate_in + 512);
  // G7: gh = enhanced @ w_hh^T + b_hh
  gemm_bt<0><<<6 * MT, dim3(512), 0, stream>>>(enhb, 512, wHh, 512, gru_b_hh,
                                               nullptr, 512, 6,
                                               gh, 1536, nullptr, 0,
                                               nullptr, nullptr, nullptr);
  // final GRU blend
  gru_final<<<NB * 64 / T, T, 0, stream>>>(gi, gh, enhf, (float*)d_out);
}

// Round 6
// 306.497 us; speedup vs baseline: 1.4811x; 1.4811x over previous
//
#include <hip/hip_runtime.h>
#include <hip/hip_bf16.h>
#include <stdint.h>

// ImprovedLatticeRNNCell fused bf16-MFMA implementation, round 6.
// Reverted to proven 128x128/BK64 GEMM (R3: 606 TF, 0 conflicts) +
// merged cvt launch + G1/G6 fusion + NEW: coalesced LDS-staged epilogue.

#define NB 16384
#define NHEADS 4

typedef __attribute__((ext_vector_type(8))) __bf16 bf16x8;
typedef __attribute__((ext_vector_type(4))) float f32x4;
typedef __attribute__((ext_vector_type(8))) unsigned short u16x8;

__device__ __forceinline__ unsigned short f2bf(float f) {
  union { float f; unsigned int u; } v; v.f = f;
  unsigned int u = v.u;
  unsigned int r = (u + 0x7fffu + ((u >> 16) & 1u)) >> 16;
  return (unsigned short)r;
}
__device__ __forceinline__ float bf2f(unsigned short h) {
  union { unsigned int u; float f; } v; v.u = ((unsigned int)h) << 16;
  return v.f;
}
__device__ __forceinline__ float sigmoidf_(float x) {
  return 1.0f / (1.0f + __expf(-x));
}

// ---------------- merged f32 -> bf16 conversion (9 jobs, 1 launch) ----------
#define J0 (512 * 128 / 8)    // W_in -> wComb head
#define J1 (1536 * 128 / 8)   // gru_w_ih -> wComb tail
#define J2 (1536 * 512 / 8)   // attn_in_w
#define J3 (512 * 512 / 8)    // attn_out_w
#define J4 (512 * 1536 / 8)   // W_gate
#define J5 (1536 * 512 / 8)   // gru_w_hh
#define J6 (NB * 128 / 8)     // x
#define J7 (NB * 512 / 8)     // hl
#define J8 (NB * 512 / 8)     // hu
#define C1 (J0)
#define C2 (C1 + J1)
#define C3 (C2 + J2)
#define C4 (C3 + J3)
#define C5 (C4 + J4)
#define C6 (C5 + J5)
#define C7 (C6 + J6)
#define C8 (C7 + J7)
#define CT (C8 + J8)

struct CvtJobs {
  const float* src[9];
  unsigned short* dst[9];
};

__global__ void cvt_multi(CvtJobs j) {
  int g = blockIdx.x * blockDim.x + threadIdx.x;
  if (g >= CT) return;
  int k, base;
  if (g < C4) {
    if (g < C2) {
      if (g < C1) { k = 0; base = 0; } else { k = 1; base = C1; }
    } else {
      if (g < C3) { k = 2; base = C2; } else { k = 3; base = C3; }
    }
  } else {
    if (g < C6) {
      if (g < C5) { k = 4; base = C4; } else { k = 5; base = C5; }
    } else {
      if (g < C7) { k = 6; base = C6; }
      else if (g < C8) { k = 7; base = C7; }
      else { k = 8; base = C8; }
    }
  }
  int local = g - base;
  const float4* s = (const float4*)j.src[k] + (size_t)local * 2;
  float4 a = s[0], b = s[1];
  u16x8 o;
  o[0] = f2bf(a.x); o[1] = f2bf(a.y); o[2] = f2bf(a.z); o[3] = f2bf(a.w);
  o[4] = f2bf(b.x); o[5] = f2bf(b.y); o[6] = f2bf(b.z); o[7] = f2bf(b.w);
  *((u16x8*)j.dst[k] + local) = o;
}

// pack hidden_prev f32 [B,512] -> bf16 into gate_in [B,1536] cols 0..511
__global__ void pack_hp(const float* __restrict__ hp,
                        unsigned short* __restrict__ gate_in) {
  int t = blockIdx.x * blockDim.x + threadIdx.x;  // B*64 threads
  int b = t >> 6;
  int j = (t & 63) * 8;
  const float4* s = (const float4*)(hp + (size_t)b * 512 + j);
  float4 a = s[0], c = s[1];
  u16x8 o;
  o[0] = f2bf(a.x); o[1] = f2bf(a.y); o[2] = f2bf(a.z); o[3] = f2bf(a.w);
  o[4] = f2bf(c.x); o[5] = f2bf(c.y); o[6] = f2bf(c.z); o[7] = f2bf(c.w);
  *(u16x8*)(gate_in + (size_t)b * 1536 + j) = o;
}

// ---------------- GEMM: C[M,N] = A[M,K](bf16) * W[N,K]^T(bf16) + bias ----------------
// 128x128 tile, BK=64, 4 waves (2x2 of 64x64), double-buffered LDS,
// counted vmcnt(8), both-sides XOR swizzle, XCD block swizzle.
__device__ __forceinline__ void gl_lds16(const unsigned short* g, unsigned short* l) {
  __builtin_amdgcn_global_load_lds(
      (const __attribute__((address_space(1))) void*)g,
      (__attribute__((address_space(3))) void*)l, 16, 0, 0);
}

// EPI 0: outb[row*ldob+col] = bf16(v)  (coalesced LDS epilogue)
// EPI 1: gate epilogue (sigmoid, enhanced blend) -> outf(f32) + outb(bf16)
// EPI 2: router: col<512 -> outb (ldob, bias), else outb2 at col-512 (ldob2, bias2)
template <int EPI>
__global__ __launch_bounds__(256, 2) void gemm_bt(
    const unsigned short* __restrict__ A, int lda,
    const unsigned short* __restrict__ W, int ldw,
    const float* __restrict__ bias, const float* __restrict__ bias2,
    int K, int ntx,
    unsigned short* __restrict__ outb, int ldob,
    unsigned short* __restrict__ outb2, int ldob2,
    float* __restrict__ outf,
    const float* __restrict__ hp,
    const unsigned short* __restrict__ scb) {
  __shared__ unsigned short As[2][128 * 64];
  __shared__ unsigned short Ws[2][128 * 64];
  const int tid = threadIdx.x;
  const int lane = tid & 63;
  const int wave = tid >> 6;

  // XCD-aware bijective swizzle (gridDim.x always a multiple of 8 here)
  const int nwg = gridDim.x;
  const int cpx = nwg >> 3;
  const int bid = blockIdx.x;
  const int id = (bid & 7) * cpx + (bid >> 3);
  const int bx = id % ntx;
  const int by = id / ntx;

  const int m0 = by * 128;
  const int n0 = bx * 128;
  const int wm = (wave >> 1) * 64;
  const int wn = (wave & 1) * 64;

  f32x4 acc[4][4] = {};

  // staging: thread covers (row=srow+32i, 16B slot sslot); source slot
  // pre-swizzled so that swizzled ds_read sees conflict-free layout.
  const int srow = tid >> 3;                 // 0..31
  const int sslot = (tid & 7) ^ (srow & 7);  // inverse-swizzled source slot
  const unsigned short* Ag = A + (size_t)(m0 + srow) * lda + sslot * 8;
  const unsigned short* Wg = W + (size_t)(n0 + srow) * ldw + sslot * 8;
  unsigned short* Asd = &As[0][tid * 8];
  unsigned short* Wsd = &Ws[0][tid * 8];

  auto stage = [&](int buf, int k0) {
#pragma unroll
    for (int i = 0; i < 4; ++i) {
      gl_lds16(Ag + (size_t)(i * 32) * lda + k0, Asd + buf * 8192 + i * 2048);
      gl_lds16(Wg + (size_t)(i * 32) * ldw + k0, Wsd + buf * 8192 + i * 2048);
    }
  };

  stage(0, 0);
  int cur = 0;
  const int lrow = lane & 15;
  const int kq = (lane >> 4) * 8;  // shorts
  const int sw = (lrow & 7) << 3;  // read-side swizzle (shorts)

  for (int k0 = 0; k0 < K; k0 += 64) {
    if (k0 + 64 < K) {
      stage(cur ^ 1, k0 + 64);
      // 8 loads/stage: wait for the 8 oldest (current buffer), keep 8 in flight
      asm volatile("s_waitcnt vmcnt(8)" ::: "memory");
    } else {
      asm volatile("s_waitcnt vmcnt(0)" ::: "memory");
    }
    __builtin_amdgcn_s_barrier();
#pragma unroll
    for (int kk = 0; kk < 2; ++kk) {
      const int kr = kk * 32 + kq;
      const int ki = kr ^ sw;
      bf16x8 af[4], wf[4];
#pragma unroll
      for (int m = 0; m < 4; ++m)
        af[m] = *(const bf16x8*)&As[cur][(wm + m * 16 + lrow) * 64 + ki];
#pragma unroll
      for (int n = 0; n < 4; ++n)
        wf[n] = *(const bf16x8*)&Ws[cur][(wn + n * 16 + lrow) * 64 + ki];
#pragma unroll
      for (int m = 0; m < 4; ++m)
#pragma unroll
        for (int n = 0; n < 4; ++n)
          acc[m][n] = __builtin_amdgcn_mfma_f32_16x16x32_bf16(af[m], wf[n],
                                                              acc[m][n], 0, 0, 0);
    }
    __builtin_amdgcn_s_barrier();
    cur ^= 1;
  }

  if constexpr (EPI == 1) {
    // gate epilogue: g = sigmoid(v); enhanced = hp + g*sc  (direct stores)
    const int r0 = m0 + wm + ((lane >> 4) << 2);
    const int c0 = n0 + wn + lrow;
#pragma unroll
    for (int n = 0; n < 4; ++n) {
      const int col = c0 + n * 16;
      const float bv = bias ? bias[col] : 0.0f;
#pragma unroll
      for (int m = 0; m < 4; ++m) {
#pragma unroll
        for (int i = 0; i < 4; ++i) {
          const int row = r0 + m * 16 + i;
          float g = sigmoidf_(acc[m][n][i] + bv);
          float sc = bf2f(scb[(size_t)row * 1536 + col]);
          float e = hp[(size_t)row * 512 + col] + g * sc;
          outf[(size_t)row * 512 + col] = e;
          outb[(size_t)row * 512 + col] = f2bf(e);
        }
      }
    }
  } else {
    // coalesced epilogue: stage 128x128 bf16 C-tile in (dead) As LDS, then
    // cooperative 16B-chunk stores with consecutive lanes on consecutive addrs.
    unsigned short* Cs = &As[0][0];  // 128*128 shorts = 32 KB (spans both bufs)
    unsigned short* ob = outb;
    int ld = ldob;
    int ncof = n0;  // global col base after routing
    const float* bp = bias;
    if constexpr (EPI == 2) {
      if (n0 >= 512) { ob = outb2; ld = ldob2; ncof = n0 - 512; bp = bias2; }
    }
    const int r0l = wm + ((lane >> 4) << 2);
    const int c0l = wn + lrow;
#pragma unroll
    for (int n = 0; n < 4; ++n) {
      const int col = c0l + n * 16;
      const float bv = bp ? bp[ncof + col] : 0.0f;
#pragma unroll
      for (int m = 0; m < 4; ++m)
#pragma unroll
        for (int i = 0; i < 4; ++i)
          Cs[(r0l + m * 16 + i) * 128 + col] = f2bf(acc[m][n][i] + bv);
    }
    __syncthreads();
#pragma unroll
    for (int jj = 0; jj < 8; ++jj) {
      int c = jj * 256 + tid;   // 2048 chunks = 128 rows x 16 chunks(16B)
      int row = c >> 4;
      int slot = c & 15;
      u16x8 v = *(const u16x8*)&Cs[row * 128 + slot * 8];
      *(u16x8*)&ob[(size_t)(m0 + row) * ld + ncof + slot * 8] = v;
    }
  }
}

// ---------------- attention over the 2 neighbor states ----------------
__global__ void attn_fuse(const unsigned short* __restrict__ qkvl,
                          const unsigned short* __restrict__ qkvu,
                          unsigned short* __restrict__ ctx) {
  int t = blockIdx.x * blockDim.x + threadIdx.x;
  int g = t >> 4;  // (b,h)
  int l = t & 15;
  int b = g >> 2, h = g & 3;
  const size_t base = (size_t)b * 1536 + h * 128 + l * 8;
  u16x8 q0 = *(const u16x8*)(qkvl + base);
  u16x8 k0 = *(const u16x8*)(qkvl + base + 512);
  u16x8 v0 = *(const u16x8*)(qkvl + base + 1024);
  u16x8 q1 = *(const u16x8*)(qkvu + base);
  u16x8 k1 = *(const u16x8*)(qkvu + base + 512);
  u16x8 v1 = *(const u16x8*)(qkvu + base + 1024);
  float s00 = 0.f, s01 = 0.f, s10 = 0.f, s11 = 0.f;
  float v0f[8], v1f[8];
#pragma unroll
  for (int i = 0; i < 8; ++i) {
    float q0f = bf2f(q0[i]), q1f = bf2f(q1[i]);
    float k0f = bf2f(k0[i]), k1f = bf2f(k1[i]);
    v0f[i] = bf2f(v0[i]); v1f[i] = bf2f(v1[i]);
    s00 += q0f * k0f; s01 += q0f * k1f;
    s10 += q1f * k0f; s11 += q1f * k1f;
  }
#pragma unroll
  for (int off = 1; off < 16; off <<= 1) {
    s00 += __shfl_xor(s00, off);
    s01 += __shfl_xor(s01, off);
    s10 += __shfl_xor(s10, off);
    s11 += __shfl_xor(s11, off);
  }
  const float scale = 0.0883883476483184f;  // 1/sqrt(128)
  s00 *= scale; s01 *= scale; s10 *= scale; s11 *= scale;
  float m0 = fmaxf(s00, s01), m1 = fmaxf(s10, s11);
  float a00 = __expf(s00 - m0), a01 = __expf(s01 - m0);
  float a10 = __expf(s10 - m1), a11 = __expf(s11 - m1);
  float c0 = 0.5f * (a00 / (a00 + a01) + a10 / (a10 + a11));
  float c1 = 0.5f * (a01 / (a00 + a01) + a11 / (a10 + a11));
  u16x8 o;
#pragma unroll
  for (int i = 0; i < 8; ++i) o[i] = f2bf(c0 * v0f[i] + c1 * v1f[i]);
  *(u16x8*)(ctx + (size_t)b * 512 + h * 128 + l * 8) = o;
}

// ---------------- GRU elementwise finish ----------------
__global__ void gru_final(const unsigned short* __restrict__ gi,
                          const unsigned short* __restrict__ gh,
                          const float* __restrict__ enh,
                          float* __restrict__ out) {
  int t = blockIdx.x * blockDim.x + threadIdx.x;  // B*64 threads
  int b = t >> 6;
  int j = (t & 63) * 8;
  size_t gb = (size_t)b * 1536 + j;
  u16x8 ir = *(const u16x8*)(gi + gb);
  u16x8 iz = *(const u16x8*)(gi + gb + 512);
  u16x8 in_ = *(const u16x8*)(gi + gb + 1024);
  u16x8 hr = *(const u16x8*)(gh + gb);
  u16x8 hz = *(const u16x8*)(gh + gb + 512);
  u16x8 hn = *(const u16x8*)(gh + gb + 1024);
  size_t eb = (size_t)b * 512 + j;
  float4 e0 = *(const float4*)(enh + eb);
  float4 e1 = *(const float4*)(enh + eb + 4);
  float ef[8] = {e0.x, e0.y, e0.z, e0.w, e1.x, e1.y, e1.z, e1.w};
  float of[8];
#pragma unroll
  for (int i = 0; i < 8; ++i) {
    float r = sigmoidf_(bf2f(ir[i]) + bf2f(hr[i]));
    float z = sigmoidf_(bf2f(iz[i]) + bf2f(hz[i]));
    float n = tanhf(bf2f(in_[i]) + r * bf2f(hn[i]));
    of[i] = (1.0f - z) * n + z * ef[i];
  }
  *(float4*)(out + eb) = make_float4(of[0], of[1], of[2], of[3]);
  *(float4*)(out + eb + 4) = make_float4(of[4], of[5], of[6], of[7]);
}

extern "C" void kernel_launch(void* const* d_in, const int* in_sizes, int n_in,
                              void* d_out, int out_size, void* d_ws, size_t ws_size,
                              hipStream_t stream) {
  const float* x = (const float*)d_in[0];
  const float* hl = (const float*)d_in[1];
  const float* hu = (const float*)d_in[2];
  const float* hp = (const float*)d_in[3];
  const float* W_in = (const float*)d_in[4];
  const float* b_in = (const float*)d_in[5];
  const float* attn_in_w = (const float*)d_in[6];
  const float* attn_in_b = (const float*)d_in[7];
  const float* attn_out_w = (const float*)d_in[8];
  const float* attn_out_b = (const float*)d_in[9];
  const float* W_gate = (const float*)d_in[10];
  const float* b_gate = (const float*)d_in[11];
  const float* gru_w_ih = (const float*)d_in[12];
  const float* gru_w_hh = (const float*)d_in[13];
  const float* gru_b_ih = (const float*)d_in[14];
  const float* gru_b_hh = (const float*)d_in[15];

  char* ws = (char*)d_ws;
  size_t off = 0;
  auto alloc = [&](size_t bytes) {
    void* p = ws + off;
    off += (bytes + 255) & ~(size_t)255;
    return p;
  };
  // bf16 weights
  unsigned short* wComb = (unsigned short*)alloc((size_t)2048 * 128 * 2);  // [W_in; gru_w_ih]
  unsigned short* wAin  = (unsigned short*)alloc((size_t)1536 * 512 * 2);
  unsigned short* wAout = (unsigned short*)alloc((size_t)512 * 512 * 2);
  unsigned short* wGate = (unsigned short*)alloc((size_t)512 * 1536 * 2);
  unsigned short* wHh   = (unsigned short*)alloc((size_t)1536 * 512 * 2);
  // bf16 activations
  unsigned short* xb   = (unsigned short*)alloc((size_t)NB * 128 * 2);
  unsigned short* hlub = (unsigned short*)alloc((size_t)2 * NB * 512 * 2);   // [hl; hu]
  unsigned short* gate_in = (unsigned short*)alloc((size_t)NB * 1536 * 2);   // [hp|sc|xp]
  unsigned short* qkvb = (unsigned short*)alloc((size_t)2 * NB * 1536 * 2);  // [qkvl; qkvu]
  unsigned short* ctxb = (unsigned short*)alloc((size_t)NB * 512 * 2);
  float* enhf = (float*)alloc((size_t)NB * 512 * 4);
  unsigned short* enhb = (unsigned short*)alloc((size_t)NB * 512 * 2);
  unsigned short* qkvl = qkvb;
  unsigned short* qkvu = qkvb + (size_t)NB * 1536;
  unsigned short* gi = qkvl;  // reuse (qkv dead after attn_fuse)
  unsigned short* gh = qkvu;

  (void)ws_size; (void)in_sizes; (void)n_in; (void)out_size;

  const int T = 256;

  // single merged conversion launch (9 jobs)
  CvtJobs jobs;
  jobs.src[0] = W_in;       jobs.dst[0] = wComb;
  jobs.src[1] = gru_w_ih;   jobs.dst[1] = wComb + (size_t)512 * 128;
  jobs.src[2] = attn_in_w;  jobs.dst[2] = wAin;
  jobs.src[3] = attn_out_w; jobs.dst[3] = wAout;
  jobs.src[4] = W_gate;     jobs.dst[4] = wGate;
  jobs.src[5] = gru_w_hh;   jobs.dst[5] = wHh;
  jobs.src[6] = x;          jobs.dst[6] = xb;
  jobs.src[7] = hl;         jobs.dst[7] = hlub;
  jobs.src[8] = hu;         jobs.dst[8] = hlub + (size_t)NB * 512;
  cvt_multi<<<(CT + T - 1) / T, T, 0, stream>>>(jobs);
  pack_hp<<<NB * 64 / T, T, 0, stream>>>(hp, gate_in);

  const int MT = NB / 128;  // 128 M-tiles

  // G2 batched: qkv for [hl;hu], M=2*NB
  gemm_bt<0><<<12 * 2 * MT, T, 0, stream>>>(hlub, 512, wAin, 512, attn_in_b,
                                            nullptr, 512, 12,
                                            qkvb, 1536, nullptr, 0,
                                            nullptr, nullptr, nullptr);
  // attention -> ctx_mean (bf16)
  attn_fuse<<<NB * NHEADS * 16 / T, T, 0, stream>>>(qkvl, qkvu, ctxb);
  // G4: spatial_combined -> gate_in cols 512..1023
  gemm_bt<0><<<4 * MT, T, 0, stream>>>(ctxb, 512, wAout, 512, attn_out_b,
                                       nullptr, 512, 4,
                                       gate_in + 512, 1536, nullptr, 0,
                                       nullptr, nullptr, nullptr);
  // G1+G6 fused: x @ [W_in; w_ih]^T, N=2048; cols<512 -> gate_in+1024, else gi
  gemm_bt<2><<<16 * MT, T, 0, stream>>>(xb, 128, wComb, 128, b_in,
                                        gru_b_ih, 128, 16,
                                        gate_in + 1024, 1536, gi, 1536,
                                        nullptr, nullptr, nullptr);
  // G5: gate + enhanced
  gemm_bt<1><<<4 * MT, T, 0, stream>>>(gate_in, 1536, wGate, 1536, b_gate,
                                       nullptr, 1536, 4,
                                       enhb, 512, nullptr, 0,
                                       enhf, hp, gate_in + 512);
  // G7: gh = enhanced @ w_hh^T + b_hh
  gemm_bt<0><<<12 * MT, T, 0, stream>>>(enhb, 512, wHh, 512, gru_b_hh,
                                        nullptr, 512, 12,
                                        gh, 1536, nullptr, 0,
                                        nullptr, nullptr, nullptr);
  // final GRU blend
  gru_final<<<NB * 64 / T, T, 0, stream>>>(gi, gh, enhf, (float*)d_out);
}